// Round 9
// baseline (221.999 us; speedup 1.0000x reference)
//
#include <hip/hip_runtime.h>

#define N_NODES 65536
#define N_EDGES 1048576
#define NB 256            // coarse buckets = dst >> 8
#define CAP 4608          // per-bucket capacity: mean 4096 + 8 sigma (binomial)
#define EPB_A 4096        // edges per block in bin pass
#define BLK_A (N_EDGES / EPB_A)   // 256
#define EPT_A (EPB_A / 1024)      // 4 edges per thread at 1024 threads
#define WT_BLK 20                 // 20 blocks x 1024 = 64*320 Wt elements
#define GEMM_BLK (N_NODES / 64)   // 1024 gemm1 node-blocks

typedef __attribute__((ext_vector_type(8))) short short8v;   // 8 bf16 (4 VGPRs)
typedef __attribute__((ext_vector_type(4))) float float4v;   // MFMA C/D

// fp32 -> bf16 round-to-nearest-even
__device__ __forceinline__ unsigned short f2bf(float f) {
  unsigned u = __float_as_uint(f);
  unsigned r = u + 0x7FFFu + ((u >> 16) & 1u);
  return (unsigned short)(r >> 16);
}
__device__ __forceinline__ float bflo(unsigned u) { return __uint_as_float(u << 16); }
__device__ __forceinline__ float bfhi(unsigned u) { return __uint_as_float(u & 0xFFFF0000u); }

// ---------------------------------------------------------------------------
// JAX threefry2x32, partitionable path: bits[i] = x0^x1 of
// threefry2x32(key=(0,42), counter=(0,i)); keep = MSB==0.  [verified R1]
// ---------------------------------------------------------------------------
__device__ __forceinline__ bool keep_mask(unsigned idx) {
  const unsigned k0 = 0u, k1 = 42u;
  const unsigned k2 = 0x1BD11BDAu ^ k0 ^ k1;
  unsigned x0 = 0u;
  unsigned x1 = idx;
  x0 += k0; x1 += k1;
#define TF_ROUND(r) { x0 += x1; x1 = (x1 << (r)) | (x1 >> (32 - (r))); x1 ^= x0; }
  TF_ROUND(13) TF_ROUND(15) TF_ROUND(26) TF_ROUND(6)
  x0 += k1; x1 += k2 + 1u;
  TF_ROUND(17) TF_ROUND(29) TF_ROUND(16) TF_ROUND(24)
  x0 += k2; x1 += k0 + 2u;
  TF_ROUND(13) TF_ROUND(15) TF_ROUND(26) TF_ROUND(6)
  x0 += k0; x1 += k1 + 3u;
  TF_ROUND(17) TF_ROUND(29) TF_ROUND(16) TF_ROUND(24)
  x0 += k1; x1 += k2 + 4u;
  TF_ROUND(13) TF_ROUND(15) TF_ROUND(26) TF_ROUND(6)
  x0 += k2; x1 += k0 + 5u;
#undef TF_ROUND
  return ((x0 ^ x1) & 0x80000000u) == 0u;
}

// ===========================================================================
// binpass2: blocks [0,256) = bucket multisplit, contiguous output run per
// block + per-(block,bucket) counts/offsets; blocks [256,276) = Wt build.
// (verbatim R8)
// ===========================================================================
__global__ __launch_bounds__(1024) void binpass2(const int* __restrict__ ei,
                                                 const float* __restrict__ ew,
                                                 const float* __restrict__ W1,
                                                 uint2* __restrict__ binned2,
                                                 unsigned* __restrict__ cnt_mat,
                                                 unsigned* __restrict__ lofs_mat,
                                                 unsigned short* __restrict__ Wt) {
  const int b = blockIdx.x;
  const int t = threadIdx.x;
  if (b >= BLK_A) {                       // Wt conversion: 20 blocks x 1024
    int i = (b - BLK_A) * 1024 + t;       // = 20480 = 64*320 exactly
    int ch = i / 320, k = i % 320;
    Wt[i] = f2bf((k < 300) ? W1[k * 64 + ch] : 0.0f);
    return;
  }
  __shared__ unsigned cnt[NB], lofs[NB], lcur[NB];
  __shared__ uint2 stage[EPB_A];
  const int e0 = b * EPB_A;
  if (t < NB) { cnt[t] = 0u; lcur[t] = 0u; }
  __syncthreads();
  unsigned pk[EPT_A], pw[EPT_A];
#pragma unroll
  for (int j = 0; j < EPT_A; ++j) {
    int e = e0 + t + j * 1024;
    unsigned s = (unsigned)ei[e];
    unsigned d = (unsigned)ei[N_EDGES + e];
    pk[j] = s | (d << 16);
    pw[j] = __float_as_uint(ew[e]);
    atomicAdd(&cnt[d >> 8], 1u);
  }
  __syncthreads();
  if (t < NB) lofs[t] = cnt[t];
  __syncthreads();
  for (int d = 1; d < NB; d <<= 1) {
    unsigned u = 0u;
    if (t < NB && t >= d) u = lofs[t - d];
    __syncthreads();
    if (t < NB) lofs[t] += u;
    __syncthreads();
  }
  if (t < NB) {
    lofs[t] -= cnt[t];                    // exclusive prefix
    cnt_mat[(unsigned)b * NB + t]  = cnt[t];
    lofs_mat[(unsigned)b * NB + t] = lofs[t];
  }
  __syncthreads();
#pragma unroll
  for (int j = 0; j < EPT_A; ++j) {
    unsigned bk = pk[j] >> 24;
    unsigned slot = lofs[bk] + atomicAdd(&lcur[bk], 1u);
    stage[slot] = make_uint2(pk[j], pw[j]);
  }
  __syncthreads();
  uint2* dst = binned2 + (size_t)b * EPB_A;
  for (int s = t; s < EPB_A; s += 1024) dst[s] = stage[s];   // coalesced
}

// ===========================================================================
// bucket_body2: per-bucket counting sort by dst low-8 (256 threads).
// R9 change: WAVE-COOPERATIVE segment gather.  16-lane groups copy one
// segment each (lane j0 reads sb+j, j += 16 -> 128B contiguous per group),
// replacing R8's per-thread serial copy (8B per cache line, 54MB FETCH).
// LDS raw layout: eLDS[CAP] @0 (36864) | scnt_s @36864 | sbase_s @37888 |
// mst_s @38912 | cnt @39936 | cur @40960 | tot @41984 -> 41988 B.
// ===========================================================================
__device__ __forceinline__ void bucket_body2(unsigned char* raw, int b,
                                             const unsigned* __restrict__ cnt_mat,
                                             const unsigned* __restrict__ lofs_mat,
                                             const uint2* __restrict__ binned2,
                                             unsigned* __restrict__ sortedc,
                                             unsigned* __restrict__ offs_p) {
  uint2*    eLDS    = (uint2*)raw;
  unsigned* scnt_s  = (unsigned*)(raw + 36864);
  unsigned* sbase_s = scnt_s + NB;
  unsigned* mst_s   = sbase_s + NB;
  unsigned* cnt     = mst_s + NB;
  unsigned* cur     = cnt + NB;
  unsigned* tot     = cur + NB;
  const int t = threadIdx.x;                 // t == source block id
  const unsigned scnt = cnt_mat[(unsigned)t * NB + b];
  const unsigned sofs = lofs_mat[(unsigned)t * NB + b];
  scnt_s[t]  = scnt;
  sbase_s[t] = (unsigned)t * EPB_A + sofs;   // element index into binned2 (< 1M)
  cnt[t] = 0u;
  cur[t] = scnt;                             // segment-size scan
  __syncthreads();
  for (int d = 1; d < NB; d <<= 1) {
    unsigned u = (t >= d) ? cur[t - d] : 0u;
    __syncthreads();
    cur[t] += u;
    __syncthreads();
  }
  mst_s[t] = cur[t] - scnt;
  if (t == NB - 1) *tot = cur[t];
  __syncthreads();
  const unsigned n_edges = *tot;
  // cooperative gather: group g (16 lanes) copies segments g, g+16, ...
  const int g = t >> 4, j0 = t & 15;
  for (int seg = g; seg < NB; seg += 16) {
    const unsigned sc = scnt_s[seg];         // LDS broadcast
    const unsigned sb = sbase_s[seg];
    const unsigned ms = mst_s[seg];
    for (unsigned j = (unsigned)j0; j < sc; j += 16)
      eLDS[ms + j] = binned2[sb + j];        // 128B contiguous per group
  }
  __syncthreads();
  for (unsigned i = t; i < n_edges; i += 256)
    atomicAdd(&cnt[(eLDS[i].x >> 16) & 255u], 1u);
  __syncthreads();
  cur[t] = cnt[t];
  __syncthreads();
  for (int d = 1; d < NB; d <<= 1) {
    unsigned u = (t >= d) ? cur[t - d] : 0u;
    __syncthreads();
    cur[t] += u;
    __syncthreads();
  }
  const unsigned lo = (unsigned)b * CAP;
  unsigned excl = cur[t] - cnt[t];
  offs_p[b * NB + t] = (lo + excl) | (cnt[t] << 21);
  __syncthreads();
  cur[t] = excl;
  __syncthreads();
  for (unsigned i = t; i < n_edges; i += 256) {
    uint2 u = eLDS[i];
    unsigned lo8 = (u.x >> 16) & 255u;
    unsigned p = lo + atomicAdd(&cur[lo8], 1u);
    sortedc[p] = (u.x & 0xFFFFu) | ((unsigned)f2bf(__uint_as_float(u.y)) << 16);
  }
}

// ===========================================================================
// gemm1_body: h1 = x @ W1 via bf16 MFMA 16x16x32; h1 stored bf16.
// LDS raw: As[64][72] @0 (9216), Bs[64][72] @9216 -> 18432 B.  (verbatim)
// ===========================================================================
__device__ __forceinline__ void gemm1_body(unsigned char* smraw, int nb,
                                           const float* __restrict__ x,
                                           const unsigned short* __restrict__ Wt,
                                           unsigned short* __restrict__ h1b) {
  unsigned short (*As)[72] = (unsigned short (*)[72])smraw;
  unsigned short (*Bs)[72] = (unsigned short (*)[72])(smraw + 9216);
  const int t = threadIdx.x;
  const int node0 = nb * 64;
  const int wave = t >> 6, lane = t & 63;
  const int quad = lane >> 4, l16 = lane & 15;
  float4v acc[4] = {{0.f,0.f,0.f,0.f},{0.f,0.f,0.f,0.f},{0.f,0.f,0.f,0.f},{0.f,0.f,0.f,0.f}};

  for (int kt = 0; kt < 5; ++kt) {
    const int k0 = kt * 64;
    for (int f = t; f < 1024; f += 256) {
      int node = f >> 4;
      int k = (f & 15) * 4;
      uint2 packed;
      if (k0 + k < 300) {
        float4 v = *(const float4*)(x + (size_t)(node0 + node) * 300 + k0 + k);
        packed.x = (unsigned)f2bf(v.x) | ((unsigned)f2bf(v.y) << 16);
        packed.y = (unsigned)f2bf(v.z) | ((unsigned)f2bf(v.w) << 16);
      } else {
        packed.x = 0u; packed.y = 0u;
      }
      *(uint2*)&As[node][k] = packed;
    }
    for (int f = t; f < 512; f += 256) {
      int ch = f >> 3;
      int kq = f & 7;
      uint4 v = *(const uint4*)(Wt + (size_t)ch * 320 + k0 + kq * 8);
      *(uint4*)&Bs[ch][kq * 8] = v;
    }
    __syncthreads();
    short8v a0 = *(const short8v*)&As[wave * 16 + l16][quad * 8];
    short8v a1 = *(const short8v*)&As[wave * 16 + l16][32 + quad * 8];
#pragma unroll
    for (int nt = 0; nt < 4; ++nt) {
      short8v b0 = *(const short8v*)&Bs[nt * 16 + l16][quad * 8];
      short8v b1 = *(const short8v*)&Bs[nt * 16 + l16][32 + quad * 8];
      acc[nt] = __builtin_amdgcn_mfma_f32_16x16x32_bf16(a0, b0, acc[nt], 0, 0, 0);
      acc[nt] = __builtin_amdgcn_mfma_f32_16x16x32_bf16(a1, b1, acc[nt], 0, 0, 0);
    }
    __syncthreads();
  }
#pragma unroll
  for (int nt = 0; nt < 4; ++nt) {
#pragma unroll
    for (int r = 0; r < 4; ++r) {
      h1b[(size_t)(node0 + wave * 16 + quad * 4 + r) * 64 + nt * 16 + l16] = f2bf(acc[nt][r]);
    }
  }
}

// ===========================================================================
// bucketsort_gemm1: blocks [0,256) = bucket_body2; blocks [256,1280) = gemm1.
// LDS union 41988 B -> 3 blocks/CU.
// ===========================================================================
__global__ __launch_bounds__(256) void bucketsort_gemm1(const unsigned* __restrict__ cnt_mat,
                                                        const unsigned* __restrict__ lofs_mat,
                                                        const uint2* __restrict__ binned2,
                                                        unsigned* __restrict__ sortedc,
                                                        unsigned* __restrict__ offs_p,
                                                        const float* __restrict__ x,
                                                        const unsigned short* __restrict__ Wt,
                                                        unsigned short* __restrict__ h1b) {
  __shared__ __align__(16) unsigned char sm[41988];
  if (blockIdx.x < NB) {
    bucket_body2(sm, blockIdx.x, cnt_mat, lofs_mat, binned2, sortedc, offs_p);
  } else {
    gemm1_body(sm, blockIdx.x - NB, x, Wt, h1b);
  }
}

// ===========================================================================
// agg1_gemm2: agg1 = b1 + sum_e w*h1[src]; h2 = mask.relu(agg1)*2; g = h2 @ W2
// (verbatim R6)
// ===========================================================================
__global__ __launch_bounds__(256) void agg1_gemm2(const unsigned* __restrict__ offs_p,
                                                  const unsigned* __restrict__ sortedc,
                                                  const unsigned short* __restrict__ h1b,
                                                  const float* __restrict__ b1,
                                                  const float* __restrict__ W2,
                                                  unsigned* __restrict__ g32u) {
  __shared__ float h2[16][68];
  __shared__ float w2t[20][68];
  const int t = threadIdx.x;
  const int node0 = blockIdx.x * 16;
  for (int i = t; i < 20 * 64; i += 256) {
    int row = i >> 6, col = i & 63;          // conflict-free LDS store
    w2t[row][col] = W2[col * 20 + row];
  }
  const int n = t >> 4, cg = t & 15;
  const int node = node0 + n;
  const unsigned op = offs_p[node];
  const unsigned s = op & 0x1FFFFFu;
  const unsigned e_end = s + (op >> 21);
  float4 acc = *(const float4*)(b1 + cg * 4);
  unsigned i = s;
  for (; i + 8 <= e_end; i += 8) {
    unsigned e0 = sortedc[i],     e1 = sortedc[i + 1], e2 = sortedc[i + 2], e3 = sortedc[i + 3];
    unsigned e4 = sortedc[i + 4], e5 = sortedc[i + 5], e6 = sortedc[i + 6], e7 = sortedc[i + 7];
    uint2 v0 = *(const uint2*)(h1b + ((size_t)(e0 & 0xFFFFu)) * 64 + cg * 4);
    uint2 v1 = *(const uint2*)(h1b + ((size_t)(e1 & 0xFFFFu)) * 64 + cg * 4);
    uint2 v2 = *(const uint2*)(h1b + ((size_t)(e2 & 0xFFFFu)) * 64 + cg * 4);
    uint2 v3 = *(const uint2*)(h1b + ((size_t)(e3 & 0xFFFFu)) * 64 + cg * 4);
    uint2 v4 = *(const uint2*)(h1b + ((size_t)(e4 & 0xFFFFu)) * 64 + cg * 4);
    uint2 v5 = *(const uint2*)(h1b + ((size_t)(e5 & 0xFFFFu)) * 64 + cg * 4);
    uint2 v6 = *(const uint2*)(h1b + ((size_t)(e6 & 0xFFFFu)) * 64 + cg * 4);
    uint2 v7 = *(const uint2*)(h1b + ((size_t)(e7 & 0xFFFFu)) * 64 + cg * 4);
    float w0 = bfhi(e0), w1 = bfhi(e1), w2 = bfhi(e2), w3 = bfhi(e3);
    float w4 = bfhi(e4), w5 = bfhi(e5), w6 = bfhi(e6), w7 = bfhi(e7);
    acc.x = fmaf(w0, bflo(v0.x), acc.x); acc.y = fmaf(w0, bfhi(v0.x), acc.y);
    acc.z = fmaf(w0, bflo(v0.y), acc.z); acc.w = fmaf(w0, bfhi(v0.y), acc.w);
    acc.x = fmaf(w1, bflo(v1.x), acc.x); acc.y = fmaf(w1, bfhi(v1.x), acc.y);
    acc.z = fmaf(w1, bflo(v1.y), acc.z); acc.w = fmaf(w1, bfhi(v1.y), acc.w);
    acc.x = fmaf(w2, bflo(v2.x), acc.x); acc.y = fmaf(w2, bfhi(v2.x), acc.y);
    acc.z = fmaf(w2, bflo(v2.y), acc.z); acc.w = fmaf(w2, bfhi(v2.y), acc.w);
    acc.x = fmaf(w3, bflo(v3.x), acc.x); acc.y = fmaf(w3, bfhi(v3.x), acc.y);
    acc.z = fmaf(w3, bflo(v3.y), acc.z); acc.w = fmaf(w3, bfhi(v3.y), acc.w);
    acc.x = fmaf(w4, bflo(v4.x), acc.x); acc.y = fmaf(w4, bfhi(v4.x), acc.y);
    acc.z = fmaf(w4, bflo(v4.y), acc.z); acc.w = fmaf(w4, bfhi(v4.y), acc.w);
    acc.x = fmaf(w5, bflo(v5.x), acc.x); acc.y = fmaf(w5, bfhi(v5.x), acc.y);
    acc.z = fmaf(w5, bflo(v5.y), acc.z); acc.w = fmaf(w5, bfhi(v5.y), acc.w);
    acc.x = fmaf(w6, bflo(v6.x), acc.x); acc.y = fmaf(w6, bfhi(v6.x), acc.y);
    acc.z = fmaf(w6, bflo(v6.y), acc.z); acc.w = fmaf(w6, bfhi(v6.y), acc.w);
    acc.x = fmaf(w7, bflo(v7.x), acc.x); acc.y = fmaf(w7, bfhi(v7.x), acc.y);
    acc.z = fmaf(w7, bflo(v7.y), acc.z); acc.w = fmaf(w7, bfhi(v7.y), acc.w);
  }
  for (; i < e_end; ++i) {
    unsigned e0 = sortedc[i];
    uint2 v0 = *(const uint2*)(h1b + ((size_t)(e0 & 0xFFFFu)) * 64 + cg * 4);
    float w0 = bfhi(e0);
    acc.x = fmaf(w0, bflo(v0.x), acc.x); acc.y = fmaf(w0, bfhi(v0.x), acc.y);
    acc.z = fmaf(w0, bflo(v0.y), acc.z); acc.w = fmaf(w0, bfhi(v0.y), acc.w);
  }
  const unsigned gi = (unsigned)node * 64u + (unsigned)cg * 4u;
  float r[4] = {acc.x, acc.y, acc.z, acc.w};
#pragma unroll
  for (int j = 0; j < 4; ++j) {
    float v = fmaxf(r[j], 0.0f);
    h2[n][cg * 4 + j] = keep_mask(gi + j) ? v * 2.0f : 0.0f;
  }
  __syncthreads();
  // gemm2 tail: lane cg computes ch {2cg, 2cg+1}; pads (cg>=10) written as 0
  float d0 = 0.0f, d1 = 0.0f;
  if (cg < 10) {
    const int c0 = cg * 2, c1 = cg * 2 + 1;
#pragma unroll
    for (int k = 0; k < 64; k += 4) {
      float4 hv = *(const float4*)(&h2[n][k]);
      float4 w0 = *(const float4*)(&w2t[c0][k]);
      float4 w1 = *(const float4*)(&w2t[c1][k]);
      d0 = fmaf(hv.x, w0.x, d0); d0 = fmaf(hv.y, w0.y, d0);
      d0 = fmaf(hv.z, w0.z, d0); d0 = fmaf(hv.w, w0.w, d0);
      d1 = fmaf(hv.x, w1.x, d1); d1 = fmaf(hv.y, w1.y, d1);
      d1 = fmaf(hv.z, w1.z, d1); d1 = fmaf(hv.w, w1.w, d1);
    }
  }
  unsigned packed = (cg < 10) ? ((unsigned)f2bf(d0) | ((unsigned)f2bf(d1) << 16)) : 0u;
  g32u[(size_t)node * 16 + cg] = packed;
}

// ===========================================================================
// aggregate2: out[n][c] = b2[c] + sum_e w * g[src][c]   (verbatim R6)
// ===========================================================================
__global__ __launch_bounds__(256) void aggregate2(const unsigned* __restrict__ offs_p,
                                                  const unsigned* __restrict__ sortedc,
                                                  const unsigned* __restrict__ g32u,
                                                  const float* __restrict__ b2,
                                                  float* __restrict__ out) {
  const int t = threadIdx.x;
  const int n = blockIdx.x * 16 + (t >> 4);
  const int cg = t & 15;
  const unsigned op = offs_p[n];
  const unsigned s = op & 0x1FFFFFu;
  const unsigned e_end = s + (op >> 21);
  float ax = 0.0f, ay = 0.0f;
  unsigned i = s;
  for (; i + 8 <= e_end; i += 8) {
    unsigned e0 = sortedc[i],     e1 = sortedc[i + 1], e2 = sortedc[i + 2], e3 = sortedc[i + 3];
    unsigned e4 = sortedc[i + 4], e5 = sortedc[i + 5], e6 = sortedc[i + 6], e7 = sortedc[i + 7];
    unsigned v0 = g32u[(size_t)(e0 & 0xFFFFu) * 16 + cg];
    unsigned v1 = g32u[(size_t)(e1 & 0xFFFFu) * 16 + cg];
    unsigned v2 = g32u[(size_t)(e2 & 0xFFFFu) * 16 + cg];
    unsigned v3 = g32u[(size_t)(e3 & 0xFFFFu) * 16 + cg];
    unsigned v4 = g32u[(size_t)(e4 & 0xFFFFu) * 16 + cg];
    unsigned v5 = g32u[(size_t)(e5 & 0xFFFFu) * 16 + cg];
    unsigned v6 = g32u[(size_t)(e6 & 0xFFFFu) * 16 + cg];
    unsigned v7 = g32u[(size_t)(e7 & 0xFFFFu) * 16 + cg];
    float w0 = bfhi(e0), w1 = bfhi(e1), w2 = bfhi(e2), w3 = bfhi(e3);
    float w4 = bfhi(e4), w5 = bfhi(e5), w6 = bfhi(e6), w7 = bfhi(e7);
    ax = fmaf(w0, bflo(v0), ax); ay = fmaf(w0, bfhi(v0), ay);
    ax = fmaf(w1, bflo(v1), ax); ay = fmaf(w1, bfhi(v1), ay);
    ax = fmaf(w2, bflo(v2), ax); ay = fmaf(w2, bfhi(v2), ay);
    ax = fmaf(w3, bflo(v3), ax); ay = fmaf(w3, bfhi(v3), ay);
    ax = fmaf(w4, bflo(v4), ax); ay = fmaf(w4, bfhi(v4), ay);
    ax = fmaf(w5, bflo(v5), ax); ay = fmaf(w5, bfhi(v5), ay);
    ax = fmaf(w6, bflo(v6), ax); ay = fmaf(w6, bfhi(v6), ay);
    ax = fmaf(w7, bflo(v7), ax); ay = fmaf(w7, bfhi(v7), ay);
  }
  for (; i < e_end; ++i) {
    unsigned e0 = sortedc[i];
    unsigned v0 = g32u[(size_t)(e0 & 0xFFFFu) * 16 + cg];
    float w0 = bfhi(e0);
    ax = fmaf(w0, bflo(v0), ax); ay = fmaf(w0, bfhi(v0), ay);
  }
  if (cg < 10) {
    float2 o = make_float2(ax + b2[cg * 2], ay + b2[cg * 2 + 1]);
    *(float2*)(out + (size_t)n * 20 + cg * 2) = o;
  }
}

extern "C" void kernel_launch(void* const* d_in, const int* in_sizes, int n_in,
                              void* d_out, int out_size, void* d_ws, size_t ws_size,
                              hipStream_t stream) {
  const float* x  = (const float*)d_in[0];
  const int*   ei = (const int*)d_in[1];
  const float* ew = (const float*)d_in[2];
  const float* W1 = (const float*)d_in[3];
  const float* b1 = (const float*)d_in[4];
  const float* W2 = (const float*)d_in[5];
  const float* b2 = (const float*)d_in[6];
  float* out = (float*)d_out;

  // workspace layout (~25.5 MB)
  unsigned short* h1b      = (unsigned short*)d_ws;                    // N*64 bf16, 8MB
  unsigned*       g32u     = (unsigned*)(h1b + (size_t)N_NODES * 64);  // N*16 uint, 4MB
  uint2*          binned2  = (uint2*)(g32u + (size_t)N_NODES * 16);    // 1M uint2, 8MB
  unsigned*       sortedc  = (unsigned*)(binned2 + (size_t)N_EDGES);   // NB*CAP uint, 4.7MB
  unsigned*       offs_p   = sortedc + (size_t)NB * CAP;               // N packed CSR
  unsigned*       cnt_mat  = offs_p + N_NODES;                         // 256x256 u32
  unsigned*       lofs_mat = cnt_mat + (size_t)BLK_A * NB;             // 256x256 u32
  unsigned short* Wt       = (unsigned short*)(lofs_mat + (size_t)BLK_A * NB); // 64*320 bf16

  binpass2<<<BLK_A + WT_BLK, 1024, 0, stream>>>(ei, ew, W1, binned2, cnt_mat, lofs_mat, Wt);
  bucketsort_gemm1<<<NB + GEMM_BLK, 256, 0, stream>>>(cnt_mat, lofs_mat, binned2,
                                                      sortedc, offs_p, x, Wt, h1b);
  agg1_gemm2<<<N_NODES / 16, 256, 0, stream>>>(offs_p, sortedc, h1b, b1, W2, g32u);
  aggregate2<<<N_NODES / 16, 256, 0, stream>>>(offs_p, sortedc, g32u, b2, out);
}

// Round 10
// 212.232 us; speedup vs baseline: 1.0460x; 1.0460x over previous
//
#include <hip/hip_runtime.h>

#define N_NODES 65536
#define N_EDGES 1048576
#define NB 256            // coarse buckets = dst >> 8
#define CAP 4608          // per-bucket capacity: mean 4096 + 8 sigma (binomial)
#define EPB_A 4096        // edges per block in bin pass
#define BLK_A (N_EDGES / EPB_A)   // 256
#define EPT_A (EPB_A / 1024)      // 4 edges per thread at 1024 threads
#define WT_BLK 20                 // 20 blocks x 1024 = 64*320 Wt elements
#define GEMM_BLK (N_NODES / 64)   // 1024 gemm1 node-blocks

typedef __attribute__((ext_vector_type(8))) short short8v;   // 8 bf16 (4 VGPRs)
typedef __attribute__((ext_vector_type(4))) float float4v;   // MFMA C/D

// fp32 -> bf16 round-to-nearest-even
__device__ __forceinline__ unsigned short f2bf(float f) {
  unsigned u = __float_as_uint(f);
  unsigned r = u + 0x7FFFu + ((u >> 16) & 1u);
  return (unsigned short)(r >> 16);
}
__device__ __forceinline__ float bflo(unsigned u) { return __uint_as_float(u << 16); }
__device__ __forceinline__ float bfhi(unsigned u) { return __uint_as_float(u & 0xFFFF0000u); }

// ---------------------------------------------------------------------------
// JAX threefry2x32, partitionable path: bits[i] = x0^x1 of
// threefry2x32(key=(0,42), counter=(0,i)); keep = MSB==0.  [verified R1]
// ---------------------------------------------------------------------------
__device__ __forceinline__ bool keep_mask(unsigned idx) {
  const unsigned k0 = 0u, k1 = 42u;
  const unsigned k2 = 0x1BD11BDAu ^ k0 ^ k1;
  unsigned x0 = 0u;
  unsigned x1 = idx;
  x0 += k0; x1 += k1;
#define TF_ROUND(r) { x0 += x1; x1 = (x1 << (r)) | (x1 >> (32 - (r))); x1 ^= x0; }
  TF_ROUND(13) TF_ROUND(15) TF_ROUND(26) TF_ROUND(6)
  x0 += k1; x1 += k2 + 1u;
  TF_ROUND(17) TF_ROUND(29) TF_ROUND(16) TF_ROUND(24)
  x0 += k2; x1 += k0 + 2u;
  TF_ROUND(13) TF_ROUND(15) TF_ROUND(26) TF_ROUND(6)
  x0 += k0; x1 += k1 + 3u;
  TF_ROUND(17) TF_ROUND(29) TF_ROUND(16) TF_ROUND(24)
  x0 += k1; x1 += k2 + 4u;
  TF_ROUND(13) TF_ROUND(15) TF_ROUND(26) TF_ROUND(6)
  x0 += k2; x1 += k0 + 5u;
#undef TF_ROUND
  return ((x0 ^ x1) & 0x80000000u) == 0u;
}

// ===========================================================================
// binpass2: blocks [0,256) = bucket multisplit.  R10: emits COMPRESSED
// streams — val2 (src | bf16w << 16, 4B) + key2 (dst low-8, 1B) — halving
// the binned traffic and letting the bucket pass stage only keys in LDS.
// Blocks [256,276) = Wt build (verbatim).
// ===========================================================================
__global__ __launch_bounds__(1024) void binpass2(const int* __restrict__ ei,
                                                 const float* __restrict__ ew,
                                                 const float* __restrict__ W1,
                                                 unsigned* __restrict__ val2,
                                                 unsigned char* __restrict__ key2,
                                                 unsigned* __restrict__ cnt_mat,
                                                 unsigned* __restrict__ lofs_mat,
                                                 unsigned short* __restrict__ Wt) {
  const int b = blockIdx.x;
  const int t = threadIdx.x;
  if (b >= BLK_A) {                       // Wt conversion: 20 blocks x 1024
    int i = (b - BLK_A) * 1024 + t;       // = 20480 = 64*320 exactly
    int ch = i / 320, k = i % 320;
    Wt[i] = f2bf((k < 300) ? W1[k * 64 + ch] : 0.0f);
    return;
  }
  __shared__ unsigned cnt[NB], lofs[NB], lcur[NB];
  __shared__ unsigned stage_val[EPB_A];        // 16 KB
  __shared__ unsigned char stage_key[EPB_A];   // 4 KB
  const int e0 = b * EPB_A;
  if (t < NB) { cnt[t] = 0u; lcur[t] = 0u; }
  __syncthreads();
  unsigned pv[EPT_A], pb[EPT_A], pk8[EPT_A];
#pragma unroll
  for (int j = 0; j < EPT_A; ++j) {
    int e = e0 + t + j * 1024;
    unsigned s = (unsigned)ei[e];
    unsigned d = (unsigned)ei[N_EDGES + e];
    pv[j]  = s | ((unsigned)f2bf(ew[e]) << 16);
    pb[j]  = d >> 8;
    pk8[j] = d & 255u;
    atomicAdd(&cnt[pb[j]], 1u);
  }
  __syncthreads();
  if (t < NB) lofs[t] = cnt[t];
  __syncthreads();
  for (int d = 1; d < NB; d <<= 1) {
    unsigned u = 0u;
    if (t < NB && t >= d) u = lofs[t - d];
    __syncthreads();
    if (t < NB) lofs[t] += u;
    __syncthreads();
  }
  if (t < NB) {
    lofs[t] -= cnt[t];                    // exclusive prefix
    cnt_mat[(unsigned)b * NB + t]  = cnt[t];
    lofs_mat[(unsigned)b * NB + t] = lofs[t];
  }
  __syncthreads();
#pragma unroll
  for (int j = 0; j < EPT_A; ++j) {
    unsigned bk = pb[j];
    unsigned slot = lofs[bk] + atomicAdd(&lcur[bk], 1u);
    stage_val[slot] = pv[j];
    stage_key[slot] = (unsigned char)pk8[j];
  }
  __syncthreads();
  unsigned* dv = val2 + (size_t)b * EPB_A;
  unsigned char* dk = key2 + (size_t)b * EPB_A;
  for (int s = t; s < EPB_A; s += 1024) { dv[s] = stage_val[s]; dk[s] = stage_key[s]; }
}

// ===========================================================================
// bucket_body3: per-bucket counting sort by dst low-8 (256 threads).
// R10: stages ONLY the 1-byte keys in LDS (4.6 KB); payload streams
// global(val2)->global(sortedc) in the scatter (write window 18KB, L2).
// Bucket LDS ~9.7 KB -> union with gemm1 = 18.4 KB -> 8 blocks/CU, the
// whole 1280-block fused grid co-resident (fixes R8/R9's occupancy limit).
// LDS raw layout: kLDS[CAP] @0 (4608) | scnt_s @4608 | sbase_s @5632 |
// mst_s @6656 | cnt @7680 | cur @8704 -> 9728 B.
// ===========================================================================
__device__ __forceinline__ void bucket_body3(unsigned char* raw, int b,
                                             const unsigned* __restrict__ cnt_mat,
                                             const unsigned* __restrict__ lofs_mat,
                                             const unsigned* __restrict__ val2,
                                             const unsigned char* __restrict__ key2,
                                             unsigned* __restrict__ sortedc,
                                             unsigned* __restrict__ offs_p) {
  unsigned char* kLDS   = raw;
  unsigned* scnt_s  = (unsigned*)(raw + 4608);
  unsigned* sbase_s = scnt_s + NB;
  unsigned* mst_s   = sbase_s + NB;
  unsigned* cnt     = mst_s + NB;
  unsigned* cur     = cnt + NB;
  const int t = threadIdx.x;                 // t == source block id
  const unsigned scnt = cnt_mat[(unsigned)t * NB + b];
  const unsigned sofs = lofs_mat[(unsigned)t * NB + b];
  scnt_s[t]  = scnt;
  sbase_s[t] = (unsigned)t * EPB_A + sofs;   // element index (< 1M)
  cnt[t] = 0u;
  cur[t] = scnt;                             // segment-size scan
  __syncthreads();
  for (int d = 1; d < NB; d <<= 1) {
    unsigned u = (t >= d) ? cur[t - d] : 0u;
    __syncthreads();
    cur[t] += u;
    __syncthreads();
  }
  mst_s[t] = cur[t] - scnt;
  __syncthreads();
  const unsigned n_edges = cur[NB - 1];
  // cooperative key gather: group g (16 lanes) copies segments g, g+16, ...
  const int g = t >> 4, j0 = t & 15;
  for (int seg = g; seg < NB; seg += 16) {
    const unsigned sc = scnt_s[seg];
    const unsigned sb = sbase_s[seg];
    const unsigned ms = mst_s[seg];
    for (unsigned j = (unsigned)j0; j < sc; j += 16)
      kLDS[ms + j] = key2[sb + j];
  }
  __syncthreads();
  for (unsigned i = t; i < n_edges; i += 256)
    atomicAdd(&cnt[kLDS[i]], 1u);
  __syncthreads();
  const unsigned myc = cnt[t];
  cur[t] = myc;
  __syncthreads();
  for (int d = 1; d < NB; d <<= 1) {
    unsigned u = (t >= d) ? cur[t - d] : 0u;
    __syncthreads();
    cur[t] += u;
    __syncthreads();
  }
  const unsigned lo = (unsigned)b * CAP;
  unsigned excl = cur[t] - myc;
  offs_p[b * NB + t] = (lo + excl) | (myc << 21);
  __syncthreads();
  cur[t] = excl;
  __syncthreads();
  // scatter: stream payload global->global (64B/group coalesced reads)
  for (int seg = g; seg < NB; seg += 16) {
    const unsigned sc = scnt_s[seg];
    const unsigned sb = sbase_s[seg];
    const unsigned ms = mst_s[seg];
    for (unsigned j = (unsigned)j0; j < sc; j += 16) {
      unsigned v = val2[sb + j];
      unsigned k = kLDS[ms + j];
      unsigned p = lo + atomicAdd(&cur[k], 1u);
      sortedc[p] = v;
    }
  }
}

// ===========================================================================
// gemm1_body: h1 = x @ W1 via bf16 MFMA 16x16x32; h1 stored bf16.
// LDS raw: As[64][72] @0 (9216), Bs[64][72] @9216 -> 18432 B.  (verbatim)
// ===========================================================================
__device__ __forceinline__ void gemm1_body(unsigned char* smraw, int nb,
                                           const float* __restrict__ x,
                                           const unsigned short* __restrict__ Wt,
                                           unsigned short* __restrict__ h1b) {
  unsigned short (*As)[72] = (unsigned short (*)[72])smraw;
  unsigned short (*Bs)[72] = (unsigned short (*)[72])(smraw + 9216);
  const int t = threadIdx.x;
  const int node0 = nb * 64;
  const int wave = t >> 6, lane = t & 63;
  const int quad = lane >> 4, l16 = lane & 15;
  float4v acc[4] = {{0.f,0.f,0.f,0.f},{0.f,0.f,0.f,0.f},{0.f,0.f,0.f,0.f},{0.f,0.f,0.f,0.f}};

  for (int kt = 0; kt < 5; ++kt) {
    const int k0 = kt * 64;
    for (int f = t; f < 1024; f += 256) {
      int node = f >> 4;
      int k = (f & 15) * 4;
      uint2 packed;
      if (k0 + k < 300) {
        float4 v = *(const float4*)(x + (size_t)(node0 + node) * 300 + k0 + k);
        packed.x = (unsigned)f2bf(v.x) | ((unsigned)f2bf(v.y) << 16);
        packed.y = (unsigned)f2bf(v.z) | ((unsigned)f2bf(v.w) << 16);
      } else {
        packed.x = 0u; packed.y = 0u;
      }
      *(uint2*)&As[node][k] = packed;
    }
    for (int f = t; f < 512; f += 256) {
      int ch = f >> 3;
      int kq = f & 7;
      uint4 v = *(const uint4*)(Wt + (size_t)ch * 320 + k0 + kq * 8);
      *(uint4*)&Bs[ch][kq * 8] = v;
    }
    __syncthreads();
    short8v a0 = *(const short8v*)&As[wave * 16 + l16][quad * 8];
    short8v a1 = *(const short8v*)&As[wave * 16 + l16][32 + quad * 8];
#pragma unroll
    for (int nt = 0; nt < 4; ++nt) {
      short8v b0 = *(const short8v*)&Bs[nt * 16 + l16][quad * 8];
      short8v b1 = *(const short8v*)&Bs[nt * 16 + l16][32 + quad * 8];
      acc[nt] = __builtin_amdgcn_mfma_f32_16x16x32_bf16(a0, b0, acc[nt], 0, 0, 0);
      acc[nt] = __builtin_amdgcn_mfma_f32_16x16x32_bf16(a1, b1, acc[nt], 0, 0, 0);
    }
    __syncthreads();
  }
#pragma unroll
  for (int nt = 0; nt < 4; ++nt) {
#pragma unroll
    for (int r = 0; r < 4; ++r) {
      h1b[(size_t)(node0 + wave * 16 + quad * 4 + r) * 64 + nt * 16 + l16] = f2bf(acc[nt][r]);
    }
  }
}

// ===========================================================================
// bucketsort_gemm1: blocks [0,256) = bucket_body3; blocks [256,1280) = gemm1.
// LDS union 18432 B -> 8 blocks/CU -> all 1280 blocks co-resident.
// ===========================================================================
__global__ __launch_bounds__(256) void bucketsort_gemm1(const unsigned* __restrict__ cnt_mat,
                                                        const unsigned* __restrict__ lofs_mat,
                                                        const unsigned* __restrict__ val2,
                                                        const unsigned char* __restrict__ key2,
                                                        unsigned* __restrict__ sortedc,
                                                        unsigned* __restrict__ offs_p,
                                                        const float* __restrict__ x,
                                                        const unsigned short* __restrict__ Wt,
                                                        unsigned short* __restrict__ h1b) {
  __shared__ __align__(16) unsigned char sm[18432];
  if (blockIdx.x < NB) {
    bucket_body3(sm, blockIdx.x, cnt_mat, lofs_mat, val2, key2, sortedc, offs_p);
  } else {
    gemm1_body(sm, blockIdx.x - NB, x, Wt, h1b);
  }
}

// ===========================================================================
// agg1_gemm2: agg1 = b1 + sum_e w*h1[src]; h2 = mask.relu(agg1)*2; g = h2 @ W2
// (verbatim R6)
// ===========================================================================
__global__ __launch_bounds__(256) void agg1_gemm2(const unsigned* __restrict__ offs_p,
                                                  const unsigned* __restrict__ sortedc,
                                                  const unsigned short* __restrict__ h1b,
                                                  const float* __restrict__ b1,
                                                  const float* __restrict__ W2,
                                                  unsigned* __restrict__ g32u) {
  __shared__ float h2[16][68];
  __shared__ float w2t[20][68];
  const int t = threadIdx.x;
  const int node0 = blockIdx.x * 16;
  for (int i = t; i < 20 * 64; i += 256) {
    int row = i >> 6, col = i & 63;          // conflict-free LDS store
    w2t[row][col] = W2[col * 20 + row];
  }
  const int n = t >> 4, cg = t & 15;
  const int node = node0 + n;
  const unsigned op = offs_p[node];
  const unsigned s = op & 0x1FFFFFu;
  const unsigned e_end = s + (op >> 21);
  float4 acc = *(const float4*)(b1 + cg * 4);
  unsigned i = s;
  for (; i + 8 <= e_end; i += 8) {
    unsigned e0 = sortedc[i],     e1 = sortedc[i + 1], e2 = sortedc[i + 2], e3 = sortedc[i + 3];
    unsigned e4 = sortedc[i + 4], e5 = sortedc[i + 5], e6 = sortedc[i + 6], e7 = sortedc[i + 7];
    uint2 v0 = *(const uint2*)(h1b + ((size_t)(e0 & 0xFFFFu)) * 64 + cg * 4);
    uint2 v1 = *(const uint2*)(h1b + ((size_t)(e1 & 0xFFFFu)) * 64 + cg * 4);
    uint2 v2 = *(const uint2*)(h1b + ((size_t)(e2 & 0xFFFFu)) * 64 + cg * 4);
    uint2 v3 = *(const uint2*)(h1b + ((size_t)(e3 & 0xFFFFu)) * 64 + cg * 4);
    uint2 v4 = *(const uint2*)(h1b + ((size_t)(e4 & 0xFFFFu)) * 64 + cg * 4);
    uint2 v5 = *(const uint2*)(h1b + ((size_t)(e5 & 0xFFFFu)) * 64 + cg * 4);
    uint2 v6 = *(const uint2*)(h1b + ((size_t)(e6 & 0xFFFFu)) * 64 + cg * 4);
    uint2 v7 = *(const uint2*)(h1b + ((size_t)(e7 & 0xFFFFu)) * 64 + cg * 4);
    float w0 = bfhi(e0), w1 = bfhi(e1), w2 = bfhi(e2), w3 = bfhi(e3);
    float w4 = bfhi(e4), w5 = bfhi(e5), w6 = bfhi(e6), w7 = bfhi(e7);
    acc.x = fmaf(w0, bflo(v0.x), acc.x); acc.y = fmaf(w0, bfhi(v0.x), acc.y);
    acc.z = fmaf(w0, bflo(v0.y), acc.z); acc.w = fmaf(w0, bfhi(v0.y), acc.w);
    acc.x = fmaf(w1, bflo(v1.x), acc.x); acc.y = fmaf(w1, bfhi(v1.x), acc.y);
    acc.z = fmaf(w1, bflo(v1.y), acc.z); acc.w = fmaf(w1, bfhi(v1.y), acc.w);
    acc.x = fmaf(w2, bflo(v2.x), acc.x); acc.y = fmaf(w2, bfhi(v2.x), acc.y);
    acc.z = fmaf(w2, bflo(v2.y), acc.z); acc.w = fmaf(w2, bfhi(v2.y), acc.w);
    acc.x = fmaf(w3, bflo(v3.x), acc.x); acc.y = fmaf(w3, bfhi(v3.x), acc.y);
    acc.z = fmaf(w3, bflo(v3.y), acc.z); acc.w = fmaf(w3, bfhi(v3.y), acc.w);
    acc.x = fmaf(w4, bflo(v4.x), acc.x); acc.y = fmaf(w4, bfhi(v4.x), acc.y);
    acc.z = fmaf(w4, bflo(v4.y), acc.z); acc.w = fmaf(w4, bfhi(v4.y), acc.w);
    acc.x = fmaf(w5, bflo(v5.x), acc.x); acc.y = fmaf(w5, bfhi(v5.x), acc.y);
    acc.z = fmaf(w5, bflo(v5.y), acc.z); acc.w = fmaf(w5, bfhi(v5.y), acc.w);
    acc.x = fmaf(w6, bflo(v6.x), acc.x); acc.y = fmaf(w6, bfhi(v6.x), acc.y);
    acc.z = fmaf(w6, bflo(v6.y), acc.z); acc.w = fmaf(w6, bfhi(v6.y), acc.w);
    acc.x = fmaf(w7, bflo(v7.x), acc.x); acc.y = fmaf(w7, bfhi(v7.x), acc.y);
    acc.z = fmaf(w7, bflo(v7.y), acc.z); acc.w = fmaf(w7, bfhi(v7.y), acc.w);
  }
  for (; i < e_end; ++i) {
    unsigned e0 = sortedc[i];
    uint2 v0 = *(const uint2*)(h1b + ((size_t)(e0 & 0xFFFFu)) * 64 + cg * 4);
    float w0 = bfhi(e0);
    acc.x = fmaf(w0, bflo(v0.x), acc.x); acc.y = fmaf(w0, bfhi(v0.x), acc.y);
    acc.z = fmaf(w0, bflo(v0.y), acc.z); acc.w = fmaf(w0, bfhi(v0.y), acc.w);
  }
  const unsigned gi = (unsigned)node * 64u + (unsigned)cg * 4u;
  float r[4] = {acc.x, acc.y, acc.z, acc.w};
#pragma unroll
  for (int j = 0; j < 4; ++j) {
    float v = fmaxf(r[j], 0.0f);
    h2[n][cg * 4 + j] = keep_mask(gi + j) ? v * 2.0f : 0.0f;
  }
  __syncthreads();
  // gemm2 tail: lane cg computes ch {2cg, 2cg+1}; pads (cg>=10) written as 0
  float d0 = 0.0f, d1 = 0.0f;
  if (cg < 10) {
    const int c0 = cg * 2, c1 = cg * 2 + 1;
#pragma unroll
    for (int k = 0; k < 64; k += 4) {
      float4 hv = *(const float4*)(&h2[n][k]);
      float4 w0 = *(const float4*)(&w2t[c0][k]);
      float4 w1 = *(const float4*)(&w2t[c1][k]);
      d0 = fmaf(hv.x, w0.x, d0); d0 = fmaf(hv.y, w0.y, d0);
      d0 = fmaf(hv.z, w0.z, d0); d0 = fmaf(hv.w, w0.w, d0);
      d1 = fmaf(hv.x, w1.x, d1); d1 = fmaf(hv.y, w1.y, d1);
      d1 = fmaf(hv.z, w1.z, d1); d1 = fmaf(hv.w, w1.w, d1);
    }
  }
  unsigned packed = (cg < 10) ? ((unsigned)f2bf(d0) | ((unsigned)f2bf(d1) << 16)) : 0u;
  g32u[(size_t)node * 16 + cg] = packed;
}

// ===========================================================================
// aggregate2: out[n][c] = b2[c] + sum_e w * g[src][c]   (verbatim R6)
// ===========================================================================
__global__ __launch_bounds__(256) void aggregate2(const unsigned* __restrict__ offs_p,
                                                  const unsigned* __restrict__ sortedc,
                                                  const unsigned* __restrict__ g32u,
                                                  const float* __restrict__ b2,
                                                  float* __restrict__ out) {
  const int t = threadIdx.x;
  const int n = blockIdx.x * 16 + (t >> 4);
  const int cg = t & 15;
  const unsigned op = offs_p[n];
  const unsigned s = op & 0x1FFFFFu;
  const unsigned e_end = s + (op >> 21);
  float ax = 0.0f, ay = 0.0f;
  unsigned i = s;
  for (; i + 8 <= e_end; i += 8) {
    unsigned e0 = sortedc[i],     e1 = sortedc[i + 1], e2 = sortedc[i + 2], e3 = sortedc[i + 3];
    unsigned e4 = sortedc[i + 4], e5 = sortedc[i + 5], e6 = sortedc[i + 6], e7 = sortedc[i + 7];
    unsigned v0 = g32u[(size_t)(e0 & 0xFFFFu) * 16 + cg];
    unsigned v1 = g32u[(size_t)(e1 & 0xFFFFu) * 16 + cg];
    unsigned v2 = g32u[(size_t)(e2 & 0xFFFFu) * 16 + cg];
    unsigned v3 = g32u[(size_t)(e3 & 0xFFFFu) * 16 + cg];
    unsigned v4 = g32u[(size_t)(e4 & 0xFFFFu) * 16 + cg];
    unsigned v5 = g32u[(size_t)(e5 & 0xFFFFu) * 16 + cg];
    unsigned v6 = g32u[(size_t)(e6 & 0xFFFFu) * 16 + cg];
    unsigned v7 = g32u[(size_t)(e7 & 0xFFFFu) * 16 + cg];
    float w0 = bfhi(e0), w1 = bfhi(e1), w2 = bfhi(e2), w3 = bfhi(e3);
    float w4 = bfhi(e4), w5 = bfhi(e5), w6 = bfhi(e6), w7 = bfhi(e7);
    ax = fmaf(w0, bflo(v0), ax); ay = fmaf(w0, bfhi(v0), ay);
    ax = fmaf(w1, bflo(v1), ax); ay = fmaf(w1, bfhi(v1), ay);
    ax = fmaf(w2, bflo(v2), ax); ay = fmaf(w2, bfhi(v2), ay);
    ax = fmaf(w3, bflo(v3), ax); ay = fmaf(w3, bfhi(v3), ay);
    ax = fmaf(w4, bflo(v4), ax); ay = fmaf(w4, bfhi(v4), ay);
    ax = fmaf(w5, bflo(v5), ax); ay = fmaf(w5, bfhi(v5), ay);
    ax = fmaf(w6, bflo(v6), ax); ay = fmaf(w6, bfhi(v6), ay);
    ax = fmaf(w7, bflo(v7), ax); ay = fmaf(w7, bfhi(v7), ay);
  }
  for (; i < e_end; ++i) {
    unsigned e0 = sortedc[i];
    unsigned v0 = g32u[(size_t)(e0 & 0xFFFFu) * 16 + cg];
    float w0 = bfhi(e0);
    ax = fmaf(w0, bflo(v0), ax); ay = fmaf(w0, bfhi(v0), ay);
  }
  if (cg < 10) {
    float2 o = make_float2(ax + b2[cg * 2], ay + b2[cg * 2 + 1]);
    *(float2*)(out + (size_t)n * 20 + cg * 2) = o;
  }
}

extern "C" void kernel_launch(void* const* d_in, const int* in_sizes, int n_in,
                              void* d_out, int out_size, void* d_ws, size_t ws_size,
                              hipStream_t stream) {
  const float* x  = (const float*)d_in[0];
  const int*   ei = (const int*)d_in[1];
  const float* ew = (const float*)d_in[2];
  const float* W1 = (const float*)d_in[3];
  const float* b1 = (const float*)d_in[4];
  const float* W2 = (const float*)d_in[5];
  const float* b2 = (const float*)d_in[6];
  float* out = (float*)d_out;

  // workspace layout (~22.5 MB)
  unsigned short* h1b      = (unsigned short*)d_ws;                    // N*64 bf16, 8MB
  unsigned*       g32u     = (unsigned*)(h1b + (size_t)N_NODES * 64);  // N*16 uint, 4MB
  unsigned*       val2     = g32u + (size_t)N_NODES * 16;              // 1M uint, 4MB
  unsigned*       sortedc  = val2 + (size_t)N_EDGES;                   // NB*CAP uint, 4.7MB
  unsigned*       offs_p   = sortedc + (size_t)NB * CAP;               // N packed CSR
  unsigned*       cnt_mat  = offs_p + N_NODES;                         // 256x256 u32
  unsigned*       lofs_mat = cnt_mat + (size_t)BLK_A * NB;             // 256x256 u32
  unsigned char*  key2     = (unsigned char*)(lofs_mat + (size_t)BLK_A * NB); // 1M bytes
  unsigned short* Wt       = (unsigned short*)(key2 + (size_t)N_EDGES);// 64*320 bf16

  binpass2<<<BLK_A + WT_BLK, 1024, 0, stream>>>(ei, ew, W1, val2, key2, cnt_mat, lofs_mat, Wt);
  bucketsort_gemm1<<<NB + GEMM_BLK, 256, 0, stream>>>(cnt_mat, lofs_mat, val2, key2,
                                                      sortedc, offs_p, x, Wt, h1b);
  agg1_gemm2<<<N_NODES / 16, 256, 0, stream>>>(offs_p, sortedc, h1b, b1, W2, g32u);
  aggregate2<<<N_NODES / 16, 256, 0, stream>>>(offs_p, sortedc, g32u, b2, out);
}